// Round 1
// baseline (2107.024 us; speedup 1.0000x reference)
//
#include <hip/hip_runtime.h>

#define N_NODES 50000
#define N_HEDGES 5000
#define NNZ 800000
#define IN_C 128
#define D1 256
#define D2 64

// ---------------- counting ----------------
__global__ void count_kernel(const int* __restrict__ nidx, const int* __restrict__ hidx,
                             float* __restrict__ deg, float* __restrict__ cnt) {
    int i = blockIdx.x * 256 + threadIdx.x;
    if (i < NNZ) {
        unsafeAtomicAdd(&deg[nidx[i]], 1.0f);
        unsafeAtomicAdd(&cnt[hidx[i]], 1.0f);
    }
}

// ---------------- scatter x -> agg_x[hedge] (128 feats) ----------------
__global__ void scatter_x(const float* __restrict__ x, const int* __restrict__ nidx,
                          const int* __restrict__ hidx, float* __restrict__ aggx) {
    int i = blockIdx.x * 256 + threadIdx.x;   // < NNZ*128 = 102.4M
    int e = i >> 7;
    int f = i & 127;
    int n = nidx[e];
    int h = hidx[e];
    unsafeAtomicAdd(&aggx[h * IN_C + f], x[n * IN_C + f]);
}

// ---------------- e1 = (Binv * agg_x) @ W1  [5000,128]@[128,256] ----------------
__global__ void gemm1(const float* __restrict__ aggx, const float* __restrict__ cnt,
                      const float* __restrict__ W1, float* __restrict__ e1) {
    __shared__ float a[4][IN_C];
    int h0 = blockIdx.x * 4;
    int tid = threadIdx.x;  // 256
    for (int t = tid; t < 4 * IN_C; t += 256) {
        int r = t >> 7, k = t & 127;
        int h = h0 + r;
        float c = cnt[h];
        float binv = (c > 0.f) ? (1.f / c) : 0.f;
        a[r][k] = aggx[h * IN_C + k] * binv;
    }
    __syncthreads();
    float acc0 = 0.f, acc1 = 0.f, acc2 = 0.f, acc3 = 0.f;
    for (int k = 0; k < IN_C; k++) {
        float w = W1[k * D1 + tid];
        acc0 += a[0][k] * w;
        acc1 += a[1][k] * w;
        acc2 += a[2][k] * w;
        acc3 += a[3][k] * w;
    }
    e1[(h0 + 0) * D1 + tid] = acc0;
    e1[(h0 + 1) * D1 + tid] = acc1;
    e1[(h0 + 2) * D1 + tid] = acc2;
    e1[(h0 + 3) * D1 + tid] = acc3;
}

// ---------------- scatter e1[hedge] -> s1[node] (256 feats) ----------------
__global__ void scatter_e1(const float* __restrict__ e1, const int* __restrict__ nidx,
                           const int* __restrict__ hidx, float* __restrict__ s1) {
    int i = blockIdx.x * 256 + threadIdx.x;   // < NNZ*256 = 204.8M
    int e = i >> 8;
    int f = i & 255;
    int n = nidx[e];
    int h = hidx[e];
    unsafeAtomicAdd(&s1[n * D1 + f], e1[h * D1 + f]);
}

// ---------------- h = relu(Dinv*s1 + b1) in place ----------------
__global__ void epi1(float* __restrict__ s1h, const float* __restrict__ deg,
                     const float* __restrict__ b1) {
    int i = blockIdx.x * 256 + threadIdx.x;   // < N_NODES*256
    int n = i >> 8, f = i & 255;
    float d = deg[n];
    float dinv = (d > 0.f) ? (1.f / d) : 0.f;
    float v = s1h[i] * dinv + b1[f];
    s1h[i] = (v > 0.f) ? v : 0.f;
}

// ---------------- scatter h[node] -> agg_h[hedge] (256 feats) ----------------
__global__ void scatter_h(const float* __restrict__ h_, const int* __restrict__ nidx,
                          const int* __restrict__ hidx, float* __restrict__ aggh) {
    int i = blockIdx.x * 256 + threadIdx.x;   // < NNZ*256
    int e = i >> 8;
    int f = i & 255;
    int n = nidx[e];
    int h = hidx[e];
    unsafeAtomicAdd(&aggh[h * D1 + f], h_[n * D1 + f]);
}

// ---------------- e2 = (Binv * agg_h) @ W2  [5000,256]@[256,64] ----------------
__global__ void gemm2(const float* __restrict__ aggh, const float* __restrict__ cnt,
                      const float* __restrict__ W2, float* __restrict__ e2) {
    __shared__ float a[4][D1];
    int h0 = blockIdx.x * 4;
    int tid = threadIdx.x;  // 256
    for (int t = tid; t < 4 * D1; t += 256) {
        int r = t >> 8, k = t & 255;
        int h = h0 + r;
        float c = cnt[h];
        float binv = (c > 0.f) ? (1.f / c) : 0.f;
        a[r][k] = aggh[h * D1 + k] * binv;
    }
    __syncthreads();
    int r = tid >> 6, j = tid & 63;
    float acc = 0.f;
    for (int k = 0; k < D1; k++) {
        acc += a[r][k] * W2[k * D2 + j];
    }
    e2[(h0 + r) * D2 + j] = acc;
}

// ---------------- scatter e2[hedge] -> out[node] (64 feats) ----------------
__global__ void scatter_e2(const float* __restrict__ e2, const int* __restrict__ nidx,
                           const int* __restrict__ hidx, float* __restrict__ out) {
    int i = blockIdx.x * 256 + threadIdx.x;   // < NNZ*64 = 51.2M
    int e = i >> 6;
    int f = i & 63;
    int n = nidx[e];
    int h = hidx[e];
    unsafeAtomicAdd(&out[n * D2 + f], e2[h * D2 + f]);
}

// ---------------- out = relu(Dinv*out + b2) in place ----------------
__global__ void epi2(float* __restrict__ out, const float* __restrict__ deg,
                     const float* __restrict__ b2) {
    int i = blockIdx.x * 256 + threadIdx.x;   // < N_NODES*64
    int n = i >> 6, f = i & 63;
    float d = deg[n];
    float dinv = (d > 0.f) ? (1.f / d) : 0.f;
    float v = out[i] * dinv + b2[f];
    out[i] = (v > 0.f) ? v : 0.f;
}

extern "C" void kernel_launch(void* const* d_in, const int* in_sizes, int n_in,
                              void* d_out, int out_size, void* d_ws, size_t ws_size,
                              hipStream_t stream) {
    const float* x   = (const float*)d_in[0];
    const int* edge  = (const int*)d_in[1];
    const int* nidx  = edge;          // edge[0, :]
    const int* hidx  = edge + NNZ;    // edge[1, :]
    const float* W1  = (const float*)d_in[2];
    const float* b1  = (const float*)d_in[3];
    const float* W2  = (const float*)d_in[4];
    const float* b2  = (const float*)d_in[5];
    float* out = (float*)d_out;

    // workspace layout (floats); zero-region first, then non-zeroed buffers
    float* ws   = (float*)d_ws;
    float* deg  = ws;                  // 50048 (padded)
    float* cnt  = deg + 50048;         // 5056 (padded)
    float* aggx = cnt + 5056;          // 5000*128   = 640000
    float* aggh = aggx + 640000;       // 5000*256   = 1280000
    float* s1h  = aggh + 1280000;      // 50000*256  = 12800000 (becomes h in place)
    size_t zeroN = 50048 + 5056 + 640000 + 1280000 + 12800000;  // 14,775,104 floats
    float* e1   = s1h + 12800000;      // 5000*256 = 1280000 (fully written, no zero)
    float* e2   = e1 + 1280000;        // 5000*64  = 320000  (fully written, no zero)
    // total ws use: 16,375,104 floats = 65.5 MB

    hipMemsetAsync(d_ws, 0, zeroN * sizeof(float), stream);
    hipMemsetAsync(d_out, 0, (size_t)out_size * sizeof(float), stream);

    count_kernel<<<(NNZ + 255) / 256, 256, 0, stream>>>(nidx, hidx, deg, cnt);
    scatter_x<<<NNZ * IN_C / 256, 256, 0, stream>>>(x, nidx, hidx, aggx);
    gemm1<<<N_HEDGES / 4, 256, 0, stream>>>(aggx, cnt, W1, e1);
    scatter_e1<<<NNZ * D1 / 256, 256, 0, stream>>>(e1, nidx, hidx, s1h);
    epi1<<<N_NODES * D1 / 256, 256, 0, stream>>>(s1h, deg, b1);
    scatter_h<<<NNZ * D1 / 256, 256, 0, stream>>>(s1h, nidx, hidx, aggh);
    gemm2<<<N_HEDGES / 4, 256, 0, stream>>>(aggh, cnt, W2, e2);
    scatter_e2<<<NNZ * D2 / 256, 256, 0, stream>>>(e2, nidx, hidx, out);
    epi2<<<N_NODES * D2 / 256, 256, 0, stream>>>(out, deg, b2);
}

// Round 2
// 740.287 us; speedup vs baseline: 2.8462x; 2.8462x over previous
//
#include <hip/hip_runtime.h>

#define N_NODES 50000
#define N_HEDGES 5000
#define NNZ 800000
#define IN_C 128
#define D1 256
#define D2 64

// ---------------- count degrees (int atomics) ----------------
__global__ void count_kernel(const int* __restrict__ nidx, const int* __restrict__ hidx,
                             int* __restrict__ cnt_n, int* __restrict__ cnt_h) {
    int i = blockIdx.x * 256 + threadIdx.x;
    if (i < NNZ) {
        atomicAdd(&cnt_n[nidx[i]], 1);
        atomicAdd(&cnt_h[hidx[i]], 1);
    }
}

// ---------------- exclusive scan, single block of 1024 ----------------
__global__ void exscan(const int* __restrict__ cnt, int* __restrict__ start, int n) {
    __shared__ int buf[1024];
    __shared__ int carry;
    int tid = threadIdx.x;
    if (tid == 0) carry = 0;
    __syncthreads();
    for (int base = 0; base < n; base += 1024) {
        int v = (base + tid < n) ? cnt[base + tid] : 0;
        buf[tid] = v;
        __syncthreads();
        for (int off = 1; off < 1024; off <<= 1) {
            int t = (tid >= off) ? buf[tid - off] : 0;
            __syncthreads();
            buf[tid] += t;
            __syncthreads();
        }
        int incl = buf[tid];
        if (base + tid < n) start[base + tid] = carry + (incl - v);
        __syncthreads();
        if (tid == 1023) carry += buf[1023];
        __syncthreads();
    }
    if (tid == 0) start[n] = carry;
}

// ---------------- fill adjacency lists ----------------
__global__ void fill_adj(const int* __restrict__ nidx, const int* __restrict__ hidx,
                         const int* __restrict__ start_n, const int* __restrict__ start_h,
                         int* __restrict__ cur_n, int* __restrict__ cur_h,
                         int* __restrict__ adj_n, int* __restrict__ adj_h) {
    int i = blockIdx.x * 256 + threadIdx.x;
    if (i < NNZ) {
        int n = nidx[i], h = hidx[i];
        int pn = atomicAdd(&cur_n[n], 1);
        adj_n[start_n[n] + pn] = h;
        int ph = atomicAdd(&cur_h[h], 1);
        adj_h[start_h[h] + ph] = n;
    }
}

// ---------------- pull: hedge <- member nodes, fused Binv ----------------
// grid = N_HEDGES blocks of F threads
template <int F>
__global__ void gather_hedge(const float* __restrict__ src, const int* __restrict__ start,
                             const int* __restrict__ adj, float* __restrict__ dst) {
    int h = blockIdx.x;
    int f = threadIdx.x;
    int s = start[h], e0 = start[h + 1];
    float acc0 = 0.f, acc1 = 0.f;
    int j = s;
    for (; j + 1 < e0; j += 2) {
        int m0 = adj[j], m1 = adj[j + 1];
        acc0 += src[m0 * F + f];
        acc1 += src[m1 * F + f];
    }
    if (j < e0) acc0 += src[adj[j] * F + f];
    int len = e0 - s;
    float binv = (len > 0) ? (1.f / (float)len) : 0.f;
    dst[h * F + f] = (acc0 + acc1) * binv;
}

// ---------------- pull: node <- incident hedges, fused Dinv + bias + relu ----------------
// 256-thread blocks, each handles 256/F nodes
template <int F>
__global__ void gather_node(const float* __restrict__ src, const int* __restrict__ start,
                            const int* __restrict__ adj, const float* __restrict__ bias,
                            float* __restrict__ dst) {
    constexpr int NPB = 256 / F;
    int n = blockIdx.x * NPB + threadIdx.x / F;
    int f = threadIdx.x & (F - 1);
    int s = start[n], e0 = start[n + 1];
    float acc0 = 0.f, acc1 = 0.f;
    int j = s;
    for (; j + 1 < e0; j += 2) {
        int h0 = adj[j], h1 = adj[j + 1];
        acc0 += src[h0 * F + f];
        acc1 += src[h1 * F + f];
    }
    if (j < e0) acc0 += src[adj[j] * F + f];
    int len = e0 - s;
    float dinv = (len > 0) ? (1.f / (float)len) : 0.f;
    float v = (acc0 + acc1) * dinv + bias[f];
    dst[n * F + f] = (v > 0.f) ? v : 0.f;
}

// ---------------- e1 = aggx @ W1  [5000,128]@[128,256] ----------------
__global__ void gemm1(const float* __restrict__ aggx, const float* __restrict__ W1,
                      float* __restrict__ e1) {
    __shared__ float a[4][IN_C];
    int h0 = blockIdx.x * 4;
    int tid = threadIdx.x;  // 256
    for (int t = tid; t < 4 * IN_C; t += 256)
        a[t >> 7][t & 127] = aggx[(h0 + (t >> 7)) * IN_C + (t & 127)];
    __syncthreads();
    float acc0 = 0.f, acc1 = 0.f, acc2 = 0.f, acc3 = 0.f;
    for (int k = 0; k < IN_C; k++) {
        float w = W1[k * D1 + tid];
        acc0 += a[0][k] * w;
        acc1 += a[1][k] * w;
        acc2 += a[2][k] * w;
        acc3 += a[3][k] * w;
    }
    e1[(h0 + 0) * D1 + tid] = acc0;
    e1[(h0 + 1) * D1 + tid] = acc1;
    e1[(h0 + 2) * D1 + tid] = acc2;
    e1[(h0 + 3) * D1 + tid] = acc3;
}

// ---------------- e2 = aggh @ W2  [5000,256]@[256,64] ----------------
__global__ void gemm2(const float* __restrict__ aggh, const float* __restrict__ W2,
                      float* __restrict__ e2) {
    __shared__ float a[4][D1];
    int h0 = blockIdx.x * 4;
    int tid = threadIdx.x;  // 256
    for (int t = tid; t < 4 * D1; t += 256)
        a[t >> 8][t & 255] = aggh[(h0 + (t >> 8)) * D1 + (t & 255)];
    __syncthreads();
    int r = tid >> 6, jj = tid & 63;
    float acc = 0.f;
    for (int k = 0; k < D1; k++) acc += a[r][k] * W2[k * D2 + jj];
    e2[(h0 + r) * D2 + jj] = acc;
}

extern "C" void kernel_launch(void* const* d_in, const int* in_sizes, int n_in,
                              void* d_out, int out_size, void* d_ws, size_t ws_size,
                              hipStream_t stream) {
    const float* x  = (const float*)d_in[0];
    const int* edge = (const int*)d_in[1];
    const int* nidx = edge;         // edge[0, :]
    const int* hidx = edge + NNZ;   // edge[1, :]
    const float* W1 = (const float*)d_in[2];
    const float* b1 = (const float*)d_in[3];
    const float* W2 = (const float*)d_in[4];
    const float* b2 = (const float*)d_in[5];
    float* out = (float*)d_out;

    // ---- workspace layout ----
    // zeroed int region first: cnt_n, cnt_h, cur_n, cur_h
    int* cnt_n = (int*)d_ws;               // 50000
    int* cnt_h = cnt_n + N_NODES;          // 5000
    int* cur_n = cnt_h + N_HEDGES;         // 50000
    int* cur_h = cur_n + N_NODES;          // 5000
    size_t zero_ints = 2 * (N_NODES + N_HEDGES);  // 110,000 ints = 440 KB
    int* start_n = cur_h + N_HEDGES;       // 50001
    int* start_h = start_n + (N_NODES + 1);// 5001
    int* adj_n = start_h + (N_HEDGES + 1); // 800000
    int* adj_h = adj_n + NNZ;              // 800000
    float* aggx = (float*)(adj_h + NNZ);   // 5000*128  = 640,000
    float* e1   = aggx + N_HEDGES * IN_C;  // 5000*256  = 1,280,000
    float* hbuf = e1 + N_HEDGES * D1;      // 50000*256 = 12,800,000
    float* aggh = hbuf + N_NODES * D1;     // 5000*256  = 1,280,000
    float* e2   = aggh + N_HEDGES * D1;    // 5000*64   = 320,000
    // total ≈ 7.0 MB ints + 65.3 MB floats ≈ 72.4 MB

    hipMemsetAsync(d_ws, 0, zero_ints * sizeof(int), stream);

    count_kernel<<<(NNZ + 255) / 256, 256, 0, stream>>>(nidx, hidx, cnt_n, cnt_h);
    exscan<<<1, 1024, 0, stream>>>(cnt_n, start_n, N_NODES);
    exscan<<<1, 1024, 0, stream>>>(cnt_h, start_h, N_HEDGES);
    fill_adj<<<(NNZ + 255) / 256, 256, 0, stream>>>(nidx, hidx, start_n, start_h,
                                                    cur_n, cur_h, adj_n, adj_h);

    gather_hedge<IN_C><<<N_HEDGES, IN_C, 0, stream>>>(x, start_h, adj_h, aggx);
    gemm1<<<N_HEDGES / 4, 256, 0, stream>>>(aggx, W1, e1);
    gather_node<D1><<<N_NODES, 256, 0, stream>>>(e1, start_n, adj_n, b1, hbuf);
    gather_hedge<D1><<<N_HEDGES, D1, 0, stream>>>(hbuf, start_h, adj_h, aggh);
    gemm2<<<N_HEDGES / 4, 256, 0, stream>>>(aggh, W2, e2);
    gather_node<D2><<<N_NODES / 4, 256, 0, stream>>>(e2, start_n, adj_n, b2, out);
}

// Round 3
// 504.103 us; speedup vs baseline: 4.1798x; 1.4685x over previous
//
#include <hip/hip_runtime.h>

#define N_NODES 50000
#define N_HEDGES 5000
#define NNZ 800000
#define IN_C 128
#define D1 256
#define D2 64

// ---------------- count degrees (int atomics) ----------------
__global__ void count_kernel(const int* __restrict__ nidx, const int* __restrict__ hidx,
                             int* __restrict__ cnt_n, int* __restrict__ cnt_h) {
    int i = blockIdx.x * 256 + threadIdx.x;
    if (i < NNZ) {
        atomicAdd(&cnt_n[nidx[i]], 1);
        atomicAdd(&cnt_h[hidx[i]], 1);
    }
}

// ---------------- hierarchical exclusive scan ----------------
// scan1: each block handles 1024 elems (4/thread); writes local-exclusive into
// start[], block total into partials[b].
__global__ void scan1(const int* __restrict__ cnt, int n, int* __restrict__ start,
                      int* __restrict__ partials) {
    __shared__ int buf[256];
    int b = blockIdx.x, tid = threadIdx.x;
    int base = b * 1024 + tid * 4;
    int v0 = (base + 0 < n) ? cnt[base + 0] : 0;
    int v1 = (base + 1 < n) ? cnt[base + 1] : 0;
    int v2 = (base + 2 < n) ? cnt[base + 2] : 0;
    int v3 = (base + 3 < n) ? cnt[base + 3] : 0;
    int tsum = v0 + v1 + v2 + v3;
    buf[tid] = tsum;
    __syncthreads();
    for (int off = 1; off < 256; off <<= 1) {
        int t = (tid >= off) ? buf[tid - off] : 0;
        __syncthreads();
        buf[tid] += t;
        __syncthreads();
    }
    int ex = buf[tid] - tsum;
    if (tid == 255) partials[b] = buf[255];
    if (base + 0 < n) start[base + 0] = ex;
    if (base + 1 < n) start[base + 1] = ex + v0;
    if (base + 2 < n) start[base + 2] = ex + v0 + v1;
    if (base + 3 < n) start[base + 3] = ex + v0 + v1 + v2;
}

// scan2: serial exclusive scan of partials (nb <= 49)
__global__ void scan2(int* __restrict__ partials, int nb) {
    if (threadIdx.x == 0) {
        int run = 0;
        for (int i = 0; i < nb; i++) { int t = partials[i]; partials[i] = run; run += t; }
    }
}

// scan3: add block offsets; write start[n] = NNZ
__global__ void scan3(int* __restrict__ start, const int* __restrict__ partials, int n) {
    int i = blockIdx.x * 256 + threadIdx.x;
    if (i < n) start[i] += partials[i >> 10];
    if (i == 0) start[n] = NNZ;
}

// ---------------- fill adjacency lists ----------------
__global__ void fill_adj(const int* __restrict__ nidx, const int* __restrict__ hidx,
                         const int* __restrict__ start_n, const int* __restrict__ start_h,
                         int* __restrict__ cur_n, int* __restrict__ cur_h,
                         int* __restrict__ adj_n, int* __restrict__ adj_h) {
    int i = blockIdx.x * 256 + threadIdx.x;
    if (i < NNZ) {
        int n = nidx[i], h = hidx[i];
        int pn = atomicAdd(&cur_n[n], 1);
        adj_n[start_n[n] + pn] = h;
        int ph = atomicAdd(&cur_h[h], 1);
        adj_h[start_h[h] + ph] = n;
    }
}

// ---------------- vec4 pull-gather, fused 1/len (+bias+relu) ----------------
// F floats per row; L = F/4 lanes per row; 256-thread blocks.
template <int F, bool BIAS_RELU>
__global__ void gather4(const float4* __restrict__ src, const int* __restrict__ start,
                        const int* __restrict__ adj, const float4* __restrict__ bias,
                        float4* __restrict__ dst) {
    constexpr int L = F / 4;
    int gid = blockIdx.x * 256 + threadIdx.x;
    int row = gid / L;
    int c = gid - row * L;
    int s = start[row], e = start[row + 1];
    float4 a0 = {0, 0, 0, 0}, a1 = {0, 0, 0, 0}, a2 = {0, 0, 0, 0}, a3 = {0, 0, 0, 0};
    int j = s;
    for (; j + 3 < e; j += 4) {
        float4 v0 = src[adj[j] * L + c];
        float4 v1 = src[adj[j + 1] * L + c];
        float4 v2 = src[adj[j + 2] * L + c];
        float4 v3 = src[adj[j + 3] * L + c];
        a0.x += v0.x; a0.y += v0.y; a0.z += v0.z; a0.w += v0.w;
        a1.x += v1.x; a1.y += v1.y; a1.z += v1.z; a1.w += v1.w;
        a2.x += v2.x; a2.y += v2.y; a2.z += v2.z; a2.w += v2.w;
        a3.x += v3.x; a3.y += v3.y; a3.z += v3.z; a3.w += v3.w;
    }
    for (; j < e; j++) {
        float4 v = src[adj[j] * L + c];
        a0.x += v.x; a0.y += v.y; a0.z += v.z; a0.w += v.w;
    }
    float inv = (e > s) ? 1.f / (float)(e - s) : 0.f;
    float4 r;
    r.x = (a0.x + a1.x + a2.x + a3.x) * inv;
    r.y = (a0.y + a1.y + a2.y + a3.y) * inv;
    r.z = (a0.z + a1.z + a2.z + a3.z) * inv;
    r.w = (a0.w + a1.w + a2.w + a3.w) * inv;
    if (BIAS_RELU) {
        float4 bb = bias[c];
        r.x = fmaxf(r.x + bb.x, 0.f);
        r.y = fmaxf(r.y + bb.y, 0.f);
        r.z = fmaxf(r.z + bb.z, 0.f);
        r.w = fmaxf(r.w + bb.w, 0.f);
    }
    dst[row * L + c] = r;
}

// ---------------- e1 = aggx @ W1  [5000,128]@[128,256] ----------------
__global__ void gemm1(const float* __restrict__ aggx, const float* __restrict__ W1,
                      float* __restrict__ e1) {
    __shared__ float a[4][IN_C];
    int h0 = blockIdx.x * 4;
    int tid = threadIdx.x;  // 256
    if (tid < 128) {
        float4 v = ((const float4*)aggx)[h0 * 32 + tid];
        int r = tid >> 5, k4 = (tid & 31) * 4;
        a[r][k4] = v.x; a[r][k4 + 1] = v.y; a[r][k4 + 2] = v.z; a[r][k4 + 3] = v.w;
    }
    __syncthreads();
    float acc0 = 0.f, acc1 = 0.f, acc2 = 0.f, acc3 = 0.f;
    for (int k = 0; k < IN_C; k++) {
        float w = W1[k * D1 + tid];
        acc0 += a[0][k] * w;
        acc1 += a[1][k] * w;
        acc2 += a[2][k] * w;
        acc3 += a[3][k] * w;
    }
    e1[(h0 + 0) * D1 + tid] = acc0;
    e1[(h0 + 1) * D1 + tid] = acc1;
    e1[(h0 + 2) * D1 + tid] = acc2;
    e1[(h0 + 3) * D1 + tid] = acc3;
}

// ---------------- e2 = aggh @ W2  [5000,256]@[256,64] ----------------
__global__ void gemm2(const float* __restrict__ aggh, const float* __restrict__ W2,
                      float* __restrict__ e2) {
    __shared__ float a[4][D1];
    int h0 = blockIdx.x * 4;
    int tid = threadIdx.x;  // 256
    {
        float4 v = ((const float4*)aggh)[h0 * 64 + tid];
        int r = tid >> 6, k4 = (tid & 63) * 4;
        a[r][k4] = v.x; a[r][k4 + 1] = v.y; a[r][k4 + 2] = v.z; a[r][k4 + 3] = v.w;
    }
    __syncthreads();
    int r = tid >> 6, jj = tid & 63;
    float acc = 0.f;
    for (int k = 0; k < D1; k++) acc += a[r][k] * W2[k * D2 + jj];
    e2[(h0 + r) * D2 + jj] = acc;
}

extern "C" void kernel_launch(void* const* d_in, const int* in_sizes, int n_in,
                              void* d_out, int out_size, void* d_ws, size_t ws_size,
                              hipStream_t stream) {
    const float* x  = (const float*)d_in[0];
    const int* edge = (const int*)d_in[1];
    const int* nidx = edge;         // edge[0, :]
    const int* hidx = edge + NNZ;   // edge[1, :]
    const float* W1 = (const float*)d_in[2];
    const float* b1 = (const float*)d_in[3];
    const float* W2 = (const float*)d_in[4];
    const float* b2 = (const float*)d_in[5];
    float* out = (float*)d_out;

    // ---- workspace layout: float4-aligned float region first, then ints ----
    float* aggx = (float*)d_ws;            // 5000*128  = 640,000
    float* e1   = aggx + N_HEDGES * IN_C;  // 5000*256  = 1,280,000
    float* hbuf = e1 + N_HEDGES * D1;      // 50000*256 = 12,800,000
    float* aggh = hbuf + N_NODES * D1;     // 5000*256  = 1,280,000
    float* e2   = aggh + N_HEDGES * D1;    // 5000*64   = 320,000
    int* ibase  = (int*)(e2 + N_HEDGES * D2);
    int* cnt_n  = ibase;                   // 50000  (zeroed)
    int* cnt_h  = cnt_n + N_NODES;         // 5000   (zeroed)
    int* cur_n  = cnt_h + N_HEDGES;        // 50000  (zeroed)
    int* cur_h  = cur_n + N_NODES;         // 5000   (zeroed)
    size_t zero_ints = 2 * (N_NODES + N_HEDGES);
    int* start_n = cur_h + N_HEDGES;       // 50001
    int* start_h = start_n + (N_NODES + 1);// 5001
    int* part_n  = start_h + (N_HEDGES + 1);// 64
    int* part_h  = part_n + 64;            // 64
    int* adj_n   = part_h + 64;            // 800000
    int* adj_h   = adj_n + NNZ;            // 800000
    // total ≈ 65.3 MB floats + 7.1 MB ints ≈ 72.4 MB

    hipMemsetAsync(cnt_n, 0, zero_ints * sizeof(int), stream);

    count_kernel<<<(NNZ + 255) / 256, 256, 0, stream>>>(nidx, hidx, cnt_n, cnt_h);

    scan1<<<(N_NODES + 1023) / 1024, 256, 0, stream>>>(cnt_n, N_NODES, start_n, part_n);
    scan2<<<1, 64, 0, stream>>>(part_n, (N_NODES + 1023) / 1024);
    scan3<<<(N_NODES + 255) / 256, 256, 0, stream>>>(start_n, part_n, N_NODES);
    scan1<<<(N_HEDGES + 1023) / 1024, 256, 0, stream>>>(cnt_h, N_HEDGES, start_h, part_h);
    scan2<<<1, 64, 0, stream>>>(part_h, (N_HEDGES + 1023) / 1024);
    scan3<<<(N_HEDGES + 255) / 256, 256, 0, stream>>>(start_h, part_h, N_HEDGES);

    fill_adj<<<(NNZ + 255) / 256, 256, 0, stream>>>(nidx, hidx, start_n, start_h,
                                                    cur_n, cur_h, adj_n, adj_h);

    // layer 1
    gather4<IN_C, false><<<N_HEDGES * (IN_C / 4) / 256, 256, 0, stream>>>(
        (const float4*)x, start_h, adj_h, nullptr, (float4*)aggx);
    gemm1<<<N_HEDGES / 4, 256, 0, stream>>>(aggx, W1, e1);
    gather4<D1, true><<<N_NODES * (D1 / 4) / 256, 256, 0, stream>>>(
        (const float4*)e1, start_n, adj_n, (const float4*)b1, (float4*)hbuf);

    // layer 2
    gather4<D1, false><<<N_HEDGES * (D1 / 4) / 256, 256, 0, stream>>>(
        (const float4*)hbuf, start_h, adj_h, nullptr, (float4*)aggh);
    gemm2<<<N_HEDGES / 4, 256, 0, stream>>>(aggh, W2, e2);
    gather4<D2, true><<<N_NODES * (D2 / 4) / 256, 256, 0, stream>>>(
        (const float4*)e2, start_n, adj_n, (const float4*)b2, (float4*)out);
}

// Round 4
// 465.004 us; speedup vs baseline: 4.5312x; 1.0841x over previous
//
#include <hip/hip_runtime.h>

#define N_NODES 50000
#define N_HEDGES 5000
#define NNZ 800000
#define IN_C 128
#define D1 256
#define D2 64

typedef unsigned int u32;
typedef unsigned short u16;

// ---- bf16 helpers: storage bf16, math f32 ----
__device__ __forceinline__ float bf_lo(u32 u) { // low 16 bits -> f32
    u32 v = u << 16; return __uint_as_float(v);
}
__device__ __forceinline__ float bf_hi(u32 u) {
    u32 v = u & 0xffff0000u; return __uint_as_float(v);
}
__device__ __forceinline__ u32 rne16(float f) { // f32 -> bf16 bits (RNE)
    u32 u = __float_as_uint(f);
    return (u + 0x7fffu + ((u >> 16) & 1u)) >> 16;
}
__device__ __forceinline__ u32 pack2(float a, float b) {
    return rne16(a) | (rne16(b) << 16);
}

// ---------------- count degrees (int atomics) ----------------
__global__ void count_kernel(const int* __restrict__ nidx, const int* __restrict__ hidx,
                             int* __restrict__ cnt_n, int* __restrict__ cnt_h) {
    int i = blockIdx.x * 256 + threadIdx.x;
    if (i < NNZ) {
        atomicAdd(&cnt_n[nidx[i]], 1);
        atomicAdd(&cnt_h[hidx[i]], 1);
    }
}

// ---------------- hierarchical exclusive scan ----------------
__global__ void scan1(const int* __restrict__ cnt, int n, int* __restrict__ start,
                      int* __restrict__ partials) {
    __shared__ int buf[256];
    int b = blockIdx.x, tid = threadIdx.x;
    int base = b * 1024 + tid * 4;
    int v0 = (base + 0 < n) ? cnt[base + 0] : 0;
    int v1 = (base + 1 < n) ? cnt[base + 1] : 0;
    int v2 = (base + 2 < n) ? cnt[base + 2] : 0;
    int v3 = (base + 3 < n) ? cnt[base + 3] : 0;
    int tsum = v0 + v1 + v2 + v3;
    buf[tid] = tsum;
    __syncthreads();
    for (int off = 1; off < 256; off <<= 1) {
        int t = (tid >= off) ? buf[tid - off] : 0;
        __syncthreads();
        buf[tid] += t;
        __syncthreads();
    }
    int ex = buf[tid] - tsum;
    if (tid == 255) partials[b] = buf[255];
    if (base + 0 < n) start[base + 0] = ex;
    if (base + 1 < n) start[base + 1] = ex + v0;
    if (base + 2 < n) start[base + 2] = ex + v0 + v1;
    if (base + 3 < n) start[base + 3] = ex + v0 + v1 + v2;
}

__global__ void scan2(int* __restrict__ partials, int nb) {
    if (threadIdx.x == 0) {
        int run = 0;
        for (int i = 0; i < nb; i++) { int t = partials[i]; partials[i] = run; run += t; }
    }
}

__global__ void scan3(int* __restrict__ start, const int* __restrict__ partials, int n) {
    int i = blockIdx.x * 256 + threadIdx.x;
    if (i < n) start[i] += partials[i >> 10];
    if (i == 0) start[n] = NNZ;
}

// ---------------- fill adjacency lists ----------------
__global__ void fill_adj(const int* __restrict__ nidx, const int* __restrict__ hidx,
                         const int* __restrict__ start_n, const int* __restrict__ start_h,
                         int* __restrict__ cur_n, int* __restrict__ cur_h,
                         int* __restrict__ adj_n, int* __restrict__ adj_h) {
    int i = blockIdx.x * 256 + threadIdx.x;
    if (i < NNZ) {
        int n = nidx[i], h = hidx[i];
        int pn = atomicAdd(&cur_n[n], 1);
        adj_n[start_n[n] + pn] = h;
        int ph = atomicAdd(&cur_h[h], 1);
        adj_h[start_h[h] + ph] = n;
    }
}

// ---------------- cast x to bf16 ----------------
__global__ void cast_x(const float4* __restrict__ x, uint2* __restrict__ xb) {
    int i = blockIdx.x * 256 + threadIdx.x;  // < N_NODES*IN_C/4
    float4 v = x[i];
    uint2 o;
    o.x = pack2(v.x, v.y);
    o.y = pack2(v.z, v.w);
    xb[i] = o;
}

// ---------------- bf16-source pull-gather, fused 1/len (+bias+relu) ----------------
// F floats per row; L = F/8 lanes per row; each lane loads uint4 = 8 bf16.
template <int F, bool BIAS_RELU, bool DST_BF16>
__global__ void gatherb(const uint4* __restrict__ src, const int* __restrict__ start,
                        const int* __restrict__ adj, const float4* __restrict__ bias,
                        void* __restrict__ dst, int nrows) {
    constexpr int L = F / 8;
    int gid = blockIdx.x * 256 + threadIdx.x;
    int row = gid / L;
    if (row >= nrows) return;
    int c = gid - row * L;
    int s = start[row], e = start[row + 1];
    float a0[8] = {0, 0, 0, 0, 0, 0, 0, 0};
    float a1[8] = {0, 0, 0, 0, 0, 0, 0, 0};
    int j = s;
    for (; j + 1 < e; j += 2) {
        uint4 v0 = src[adj[j] * L + c];
        uint4 v1 = src[adj[j + 1] * L + c];
        a0[0] += bf_lo(v0.x); a0[1] += bf_hi(v0.x);
        a0[2] += bf_lo(v0.y); a0[3] += bf_hi(v0.y);
        a0[4] += bf_lo(v0.z); a0[5] += bf_hi(v0.z);
        a0[6] += bf_lo(v0.w); a0[7] += bf_hi(v0.w);
        a1[0] += bf_lo(v1.x); a1[1] += bf_hi(v1.x);
        a1[2] += bf_lo(v1.y); a1[3] += bf_hi(v1.y);
        a1[4] += bf_lo(v1.z); a1[5] += bf_hi(v1.z);
        a1[6] += bf_lo(v1.w); a1[7] += bf_hi(v1.w);
    }
    if (j < e) {
        uint4 v0 = src[adj[j] * L + c];
        a0[0] += bf_lo(v0.x); a0[1] += bf_hi(v0.x);
        a0[2] += bf_lo(v0.y); a0[3] += bf_hi(v0.y);
        a0[4] += bf_lo(v0.z); a0[5] += bf_hi(v0.z);
        a0[6] += bf_lo(v0.w); a0[7] += bf_hi(v0.w);
    }
    float inv = (e > s) ? 1.f / (float)(e - s) : 0.f;
    float r[8];
#pragma unroll
    for (int t = 0; t < 8; t++) r[t] = (a0[t] + a1[t]) * inv;
    if (BIAS_RELU) {
        float4 b0 = bias[c * 2], b1v = bias[c * 2 + 1];
        r[0] = fmaxf(r[0] + b0.x, 0.f); r[1] = fmaxf(r[1] + b0.y, 0.f);
        r[2] = fmaxf(r[2] + b0.z, 0.f); r[3] = fmaxf(r[3] + b0.w, 0.f);
        r[4] = fmaxf(r[4] + b1v.x, 0.f); r[5] = fmaxf(r[5] + b1v.y, 0.f);
        r[6] = fmaxf(r[6] + b1v.z, 0.f); r[7] = fmaxf(r[7] + b1v.w, 0.f);
    }
    if (DST_BF16) {
        uint4 o;
        o.x = pack2(r[0], r[1]);
        o.y = pack2(r[2], r[3]);
        o.z = pack2(r[4], r[5]);
        o.w = pack2(r[6], r[7]);
        ((uint4*)dst)[row * L + c] = o;
    } else {
        float4* d = (float4*)dst;
        d[row * (F / 4) + c * 2]     = make_float4(r[0], r[1], r[2], r[3]);
        d[row * (F / 4) + c * 2 + 1] = make_float4(r[4], r[5], r[6], r[7]);
    }
}

// ---------------- f32 pull-gather (final layer), fused Dinv+bias+relu ----------------
template <int F, bool BIAS_RELU>
__global__ void gather4(const float4* __restrict__ src, const int* __restrict__ start,
                        const int* __restrict__ adj, const float4* __restrict__ bias,
                        float4* __restrict__ dst) {
    constexpr int L = F / 4;
    int gid = blockIdx.x * 256 + threadIdx.x;
    int row = gid / L;
    int c = gid - row * L;
    int s = start[row], e = start[row + 1];
    float4 a0 = {0, 0, 0, 0}, a1 = {0, 0, 0, 0};
    int j = s;
    for (; j + 1 < e; j += 2) {
        float4 v0 = src[adj[j] * L + c];
        float4 v1 = src[adj[j + 1] * L + c];
        a0.x += v0.x; a0.y += v0.y; a0.z += v0.z; a0.w += v0.w;
        a1.x += v1.x; a1.y += v1.y; a1.z += v1.z; a1.w += v1.w;
    }
    if (j < e) {
        float4 v = src[adj[j] * L + c];
        a0.x += v.x; a0.y += v.y; a0.z += v.z; a0.w += v.w;
    }
    float inv = (e > s) ? 1.f / (float)(e - s) : 0.f;
    float4 r;
    r.x = (a0.x + a1.x) * inv;
    r.y = (a0.y + a1.y) * inv;
    r.z = (a0.z + a1.z) * inv;
    r.w = (a0.w + a1.w) * inv;
    if (BIAS_RELU) {
        float4 bb = bias[c];
        r.x = fmaxf(r.x + bb.x, 0.f);
        r.y = fmaxf(r.y + bb.y, 0.f);
        r.z = fmaxf(r.z + bb.z, 0.f);
        r.w = fmaxf(r.w + bb.w, 0.f);
    }
    dst[row * L + c] = r;
}

// ---------------- e1 = aggx @ W1  [5000,128]@[128,256], bf16 out ----------------
__global__ void gemm1(const float* __restrict__ aggx, const float* __restrict__ W1,
                      u16* __restrict__ e1b) {
    __shared__ float a[4][IN_C];
    int h0 = blockIdx.x * 4;
    int tid = threadIdx.x;  // 256
    if (tid < 128) {
        float4 v = ((const float4*)aggx)[h0 * 32 + tid];
        int r = tid >> 5, k4 = (tid & 31) * 4;
        a[r][k4] = v.x; a[r][k4 + 1] = v.y; a[r][k4 + 2] = v.z; a[r][k4 + 3] = v.w;
    }
    __syncthreads();
    float acc0 = 0.f, acc1 = 0.f, acc2 = 0.f, acc3 = 0.f;
    for (int k = 0; k < IN_C; k++) {
        float w = W1[k * D1 + tid];
        acc0 += a[0][k] * w;
        acc1 += a[1][k] * w;
        acc2 += a[2][k] * w;
        acc3 += a[3][k] * w;
    }
    e1b[(h0 + 0) * D1 + tid] = (u16)rne16(acc0);
    e1b[(h0 + 1) * D1 + tid] = (u16)rne16(acc1);
    e1b[(h0 + 2) * D1 + tid] = (u16)rne16(acc2);
    e1b[(h0 + 3) * D1 + tid] = (u16)rne16(acc3);
}

// ---------------- e2 = aggh @ W2  [5000,256]@[256,64] ----------------
__global__ void gemm2(const float* __restrict__ aggh, const float* __restrict__ W2,
                      float* __restrict__ e2) {
    __shared__ float a[4][D1];
    int h0 = blockIdx.x * 4;
    int tid = threadIdx.x;  // 256
    {
        float4 v = ((const float4*)aggh)[h0 * 64 + tid];
        int r = tid >> 6, k4 = (tid & 63) * 4;
        a[r][k4] = v.x; a[r][k4 + 1] = v.y; a[r][k4 + 2] = v.z; a[r][k4 + 3] = v.w;
    }
    __syncthreads();
    int r = tid >> 6, jj = tid & 63;
    float acc = 0.f;
    for (int k = 0; k < D1; k++) acc += a[r][k] * W2[k * D2 + jj];
    e2[(h0 + r) * D2 + jj] = acc;
}

extern "C" void kernel_launch(void* const* d_in, const int* in_sizes, int n_in,
                              void* d_out, int out_size, void* d_ws, size_t ws_size,
                              hipStream_t stream) {
    const float* x  = (const float*)d_in[0];
    const int* edge = (const int*)d_in[1];
    const int* nidx = edge;         // edge[0, :]
    const int* hidx = edge + NNZ;   // edge[1, :]
    const float* W1 = (const float*)d_in[2];
    const float* b1 = (const float*)d_in[3];
    const float* W2 = (const float*)d_in[4];
    const float* b2 = (const float*)d_in[5];
    float* out = (float*)d_out;

    // ---- workspace layout (16B-aligned chunks) ----
    float* aggx = (float*)d_ws;              // 5000*128 f32  = 640,000
    float* aggh = aggx + N_HEDGES * IN_C;    // 5000*256 f32  = 1,280,000
    float* e2   = aggh + N_HEDGES * D1;      // 5000*64  f32  = 320,000
    u16* xb     = (u16*)(e2 + N_HEDGES * D2);// 50000*128 u16 = 6,400,000
    u16* e1b    = xb + N_NODES * IN_C;       // 5000*256  u16 = 1,280,000
    u16* hb     = e1b + N_HEDGES * D1;       // 50000*256 u16 = 12,800,000
    int* cnt_n  = (int*)(hb + N_NODES * D1); // 50000 (zeroed)
    int* cnt_h  = cnt_n + N_NODES;           // 5000  (zeroed)
    int* cur_n  = cnt_h + N_HEDGES;          // 50000 (zeroed)
    int* cur_h  = cur_n + N_NODES;           // 5000  (zeroed)
    size_t zero_ints = 2 * (N_NODES + N_HEDGES);
    int* start_n = cur_h + N_HEDGES;         // 50001
    int* start_h = start_n + (N_NODES + 1);  // 5001
    int* part_n  = start_h + (N_HEDGES + 1); // 64
    int* part_h  = part_n + 64;              // 64
    int* adj_n   = part_h + 64;              // 800000
    int* adj_h   = adj_n + NNZ;              // 800000
    // total ≈ 9.0 MB f32 + 41.0 MB u16 + 7.1 MB ints ≈ 57 MB

    hipMemsetAsync(cnt_n, 0, zero_ints * sizeof(int), stream);

    count_kernel<<<(NNZ + 255) / 256, 256, 0, stream>>>(nidx, hidx, cnt_n, cnt_h);

    scan1<<<(N_NODES + 1023) / 1024, 256, 0, stream>>>(cnt_n, N_NODES, start_n, part_n);
    scan2<<<1, 64, 0, stream>>>(part_n, (N_NODES + 1023) / 1024);
    scan3<<<(N_NODES + 255) / 256, 256, 0, stream>>>(start_n, part_n, N_NODES);
    scan1<<<(N_HEDGES + 1023) / 1024, 256, 0, stream>>>(cnt_h, N_HEDGES, start_h, part_h);
    scan2<<<1, 64, 0, stream>>>(part_h, (N_HEDGES + 1023) / 1024);
    scan3<<<(N_HEDGES + 255) / 256, 256, 0, stream>>>(start_h, part_h, N_HEDGES);

    fill_adj<<<(NNZ + 255) / 256, 256, 0, stream>>>(nidx, hidx, start_n, start_h,
                                                    cur_n, cur_h, adj_n, adj_h);

    cast_x<<<N_NODES * IN_C / 4 / 256, 256, 0, stream>>>((const float4*)x, (uint2*)xb);

    // layer 1
    gatherb<IN_C, false, false><<<(N_HEDGES * (IN_C / 8) + 255) / 256, 256, 0, stream>>>(
        (const uint4*)xb, start_h, adj_h, nullptr, aggx, N_HEDGES);
    gemm1<<<N_HEDGES / 4, 256, 0, stream>>>(aggx, W1, e1b);
    gatherb<D1, true, true><<<N_NODES * (D1 / 8) / 256, 256, 0, stream>>>(
        (const uint4*)e1b, start_n, adj_n, (const float4*)b1, hb, N_NODES);

    // layer 2
    gatherb<D1, false, false><<<N_HEDGES * (D1 / 8) / 256, 256, 0, stream>>>(
        (const uint4*)hb, start_h, adj_h, nullptr, aggh, N_HEDGES);
    gemm2<<<N_HEDGES / 4, 256, 0, stream>>>(aggh, W2, e2);
    gather4<D2, true><<<N_NODES * (D2 / 4) / 256, 256, 0, stream>>>(
        (const float4*)e2, start_n, adj_n, (const float4*)b2, (float4*)out);
}